// Round 10
// baseline (207.478 us; speedup 1.0000x reference)
//
#include <hip/hip_runtime.h>

#define N_NODES 100000
#define N_EDGES 1600000
#define EMBED_DIM 64

#define RPB 128                                    // rows per bucket
#define NBKT ((N_NODES + RPB - 1) / RPB)           // 782
#define NXCD 8
#define SCAP 448                                   // slots per (bucket,xcd): mean 257 + 12 sigma
#define BSPAN (NXCD * SCAP)                        // 3584 slots per bucket (contiguous)
#define TILE 2048                                  // edges per binA block
#define NTILE ((N_EDGES + TILE - 1) / TILE)        // 782
#define OVCAP 131072                               // overflow backstop (2 MB)

// ---------- pass 0: X fp32 -> bf16 (RNE) ----------
__global__ __launch_bounds__(256) void k_xcast(const float* __restrict__ x,
                                               unsigned short* __restrict__ xb) {
    int i = blockIdx.x * 256 + threadIdx.x;  // float4 index
    const int n4 = N_NODES * EMBED_DIM / 4;
    if (i >= n4) return;
    float4 f = ((const float4*)x)[i];
    unsigned b0 = __float_as_uint(f.x), b1 = __float_as_uint(f.y);
    unsigned b2 = __float_as_uint(f.z), b3 = __float_as_uint(f.w);
    ushort4 h;
    h.x = (unsigned short)((b0 + 0x7FFFu + ((b0 >> 16) & 1)) >> 16);
    h.y = (unsigned short)((b1 + 0x7FFFu + ((b1 >> 16) & 1)) >> 16);
    h.z = (unsigned short)((b2 + 0x7FFFu + ((b2 >> 16) & 1)) >> 16);
    h.w = (unsigned short)((b3 + 0x7FFFu + ((b3 >> 16) & 1)) >> 16);
    ((ushort4*)xb)[i] = h;
}

// ---------- pass 1: XCD-segregated bucket append ----------
// Region (b, xcd): all concurrent writers share one XCD's L2 -> tail lines
// fill within a single L2 -> dense writeback (fixes r9's 4x write amp).
__global__ __launch_bounds__(256) void k_binA(const int* __restrict__ rows,
                                              const int* __restrict__ cols,
                                              const float* __restrict__ vals,
                                              int* __restrict__ gcur,
                                              int2* __restrict__ packed,
                                              int* __restrict__ ov_cnt,
                                              int4* __restrict__ ov) {
    __shared__ int hist[NBKT];
    __shared__ int cur[NBKT];
    const int tid = threadIdx.x;
    const int e0 = blockIdx.x * TILE;
    const int nt = (N_EDGES - e0 < TILE) ? (N_EDGES - e0) : TILE;

    unsigned xcd;
    asm volatile("s_getreg_b32 %0, hwreg(HW_REG_XCC_ID)" : "=s"(xcd));
    xcd &= (NXCD - 1);   // any value 0..7 is correct; real id gives L2 locality

    for (int i = tid; i < NBKT; i += 256) hist[i] = 0;
    __syncthreads();
    for (int i = tid; i < nt; i += 256) atomicAdd(&hist[rows[e0 + i] >> 7], 1);
    __syncthreads();
    for (int b = tid; b < NBKT; b += 256) {
        int c = hist[b];
        if (c) cur[b] = atomicAdd(&gcur[b * NXCD + xcd], c);
    }
    __syncthreads();
    for (int i = tid; i < nt; i += 256) {
        int e = e0 + i;
        int r = rows[e];
        int b = r >> 7;
        int c = cols[e];
        int ls = atomicAdd(&cur[b], 1);
        if (ls < SCAP) {
            packed[((size_t)b * NXCD + xcd) * SCAP + ls] =
                make_int2(((r & (RPB - 1)) << 17) | c, __float_as_int(vals[e]));
        } else {  // statistically-never overflow (kept for arbitrary dispatch)
            int ovi = atomicAdd(ov_cnt, 1);
            if (ovi < OVCAP) ov[ovi] = make_int4(r, c, __float_as_int(vals[e]), 0);
        }
    }
}

// ---------- pass 2: merge 8 sub-segments, row-sort in-place, emit CSR ----------
__global__ __launch_bounds__(256) void k_binB(const int* __restrict__ gcur,
                                              int2* __restrict__ packed,
                                              int* __restrict__ row_ptr,
                                              int* __restrict__ cnt) {
    __shared__ int2 stage[BSPAN];        // 28.7 KB (total can never exceed BSPAN)
    __shared__ int h[RPB], s[RPB], cur[RPB];
    const int b = blockIdx.x;
    const int tid = threadIdx.x;
    const size_t base = (size_t)b * BSPAN;

    if (tid < RPB) h[tid] = 0;
    __syncthreads();

    // merge-load the 8 sub-segments (each contiguous, coalesced)
    int off = 0;
    for (int xx = 0; xx < NXCD; ++xx) {
        int cx = gcur[b * NXCD + xx];
        if (cx > SCAP) cx = SCAP;
        const int2* src = packed + base + (size_t)xx * SCAP;
        for (int j = tid; j < cx; j += 256) {
            int2 e = src[j];
            stage[off + j] = e;
            atomicAdd(&h[((unsigned)e.x) >> 17], 1);
        }
        off += cx;
    }
    int n = off;
    __syncthreads();

    int hv = 0;
    if (tid < RPB) { hv = h[tid]; s[tid] = hv; }
    __syncthreads();
    for (int o = 1; o < RPB; o <<= 1) {
        int add = 0;
        if (tid < RPB && tid >= o) add = s[tid - o];
        __syncthreads();
        if (tid < RPB && tid >= o) s[tid] += add;
        __syncthreads();
    }
    if (tid < RPB) {
        int ofs = s[tid] - hv;           // exclusive
        cur[tid] = ofs;
        int r = b * RPB + tid;
        if (r < N_NODES) { row_ptr[r] = (int)base + ofs; cnt[r] = hv; }
    }
    __syncthreads();

    // in-place sorted rewrite (all reads done; writes stay inside own span)
    for (int j = tid; j < n; j += 256) {
        int2 e = stage[j];
        int p = atomicAdd(&cur[((unsigned)e.x) >> 17], 1);
        packed[base + p] = make_int2(e.x & 0x1FFFF, e.y);   // strip lrow
    }
}

// ---------- pass 3: one wave per row; scalar edge loads + bf16 gather ----------
__global__ __launch_bounds__(256) void k_gather_bf16(
    const unsigned short* __restrict__ xb,
    const int* __restrict__ row_ptr, const int* __restrict__ cnt,
    const int2* __restrict__ ep, float* __restrict__ out) {
    int wid = (blockIdx.x * 256 + threadIdx.x) >> 6;
    int lane = threadIdx.x & 63;
    if (wid >= N_NODES) return;
    int beg = __builtin_amdgcn_readfirstlane(row_ptr[wid]);
    int deg = __builtin_amdgcn_readfirstlane(cnt[wid]);
    const int2* p = ep + beg;
    float acc = 0.f;
    int k = 0;
    for (; k + 8 <= deg; k += 8) {
        int2 e[8];
#pragma unroll
        for (int i = 0; i < 8; ++i) e[i] = p[k + i];    // scalar s_load
        float xv[8];
#pragma unroll
        for (int i = 0; i < 8; ++i)
            xv[i] = __uint_as_float((unsigned)xb[(e[i].x << 6) + lane] << 16);
#pragma unroll
        for (int i = 0; i < 8; ++i) acc += __int_as_float(e[i].y) * xv[i];
    }
    for (; k < deg; ++k) {
        int2 e = p[k];
        acc += __int_as_float(e.y) *
               __uint_as_float((unsigned)xb[(e.x << 6) + lane] << 16);
    }
    out[wid * EMBED_DIM + lane] = acc;
}

// ---------- fp32 gather (mid path when ws can't fit xb) ----------
__global__ __launch_bounds__(256) void k_gather_f32(
    const float* __restrict__ x,
    const int* __restrict__ row_ptr, const int* __restrict__ cnt,
    const int2* __restrict__ ep, float* __restrict__ out) {
    int wid = (blockIdx.x * 256 + threadIdx.x) >> 6;
    int lane = threadIdx.x & 63;
    if (wid >= N_NODES) return;
    int beg = __builtin_amdgcn_readfirstlane(row_ptr[wid]);
    int deg = __builtin_amdgcn_readfirstlane(cnt[wid]);
    const int2* p = ep + beg;
    float acc = 0.f;
    int k = 0;
    for (; k + 8 <= deg; k += 8) {
        int2 e[8];
#pragma unroll
        for (int i = 0; i < 8; ++i) e[i] = p[k + i];
        float xv[8];
#pragma unroll
        for (int i = 0; i < 8; ++i) xv[i] = x[(e[i].x << 6) + lane];
#pragma unroll
        for (int i = 0; i < 8; ++i) acc += __int_as_float(e[i].y) * xv[i];
    }
    for (; k < deg; ++k) {
        int2 e = p[k];
        acc += __int_as_float(e.y) * x[(e.x << 6) + lane];
    }
    out[wid * EMBED_DIM + lane] = acc;
}

// ---------- overflow cleanup (expected n==0; exact fp32) ----------
__global__ __launch_bounds__(256) void k_overflow(const float* __restrict__ x,
                                                  const int* __restrict__ ov_cnt,
                                                  const int4* __restrict__ ov,
                                                  float* __restrict__ out) {
    int n = *ov_cnt;
    if (n > OVCAP) n = OVCAP;
    int lane = threadIdx.x & 63;
    for (int idx = (blockIdx.x * 256 + threadIdx.x) >> 6; idx < n;
         idx += gridDim.x * 4) {
        int4 e = ov[idx];
        atomicAdd(&out[e.x * EMBED_DIM + lane],
                  __int_as_float(e.z) * x[e.y * EMBED_DIM + lane]);
    }
}

// ---------- fallback (ws too small): atomic scatter ----------
__global__ __launch_bounds__(256) void spmm_scatter_kernel(
    const float* __restrict__ x, const float* __restrict__ vals,
    const int* __restrict__ rows, const int* __restrict__ cols,
    float* __restrict__ out) {
    const int wave_in_block = threadIdx.x >> 6;
    const int lane = threadIdx.x & 63;
    const int e = blockIdx.x * 4 + wave_in_block;
    if (e >= N_EDGES) return;
    const float m = vals[e] * x[cols[e] * EMBED_DIM + lane];
    atomicAdd(&out[rows[e] * EMBED_DIM + lane], m);
}

extern "C" void kernel_launch(void* const* d_in, const int* in_sizes, int n_in,
                              void* d_out, int out_size, void* d_ws, size_t ws_size,
                              hipStream_t stream) {
    const float* x    = (const float*)d_in[0];
    const float* vals = (const float*)d_in[1];
    const int*   rows = (const int*)d_in[2];
    const int*   cols = (const int*)d_in[3];
    float* out = (float*)d_out;

    // ws: packed int2[NBKT*BSPAN] | xb ushort[N*64]? | ov int4[OVCAP] |
    //     gcur[NBKT*8] | ov_cnt | row_ptr[N] | cnt[N]
    const size_t packed_b = (size_t)NBKT * BSPAN * 8;        // 22,421,504
    const size_t xb_b     = (size_t)N_NODES * EMBED_DIM * 2; // 12,800,000
    const size_t ov_b     = (size_t)OVCAP * 16;              //  2,097,152
    const size_t tail_b   = ((size_t)NBKT * NXCD + 1 + 2 * (size_t)N_NODES) * 4;
    const size_t need_full = packed_b + xb_b + ov_b + tail_b;  // ~38.1 MB
    const size_t need_mid  = packed_b + ov_b + tail_b;         // ~25.3 MB

    if (ws_size < need_mid) {
        hipMemsetAsync(out, 0, (size_t)out_size * sizeof(float), stream);
        spmm_scatter_kernel<<<(N_EDGES + 3) / 4, 256, 0, stream>>>(x, vals, rows, cols, out);
        return;
    }
    const bool use_bf16 = (ws_size >= need_full);

    int2* packed = (int2*)d_ws;
    char* cursor_p = (char*)d_ws + packed_b;
    unsigned short* xbuf = (unsigned short*)cursor_p;
    if (use_bf16) cursor_p += xb_b;
    int4* ov     = (int4*)cursor_p;
    int*  gcur   = (int*)(cursor_p + ov_b);
    int*  ov_cnt = gcur + NBKT * NXCD;
    int*  row_ptr = ov_cnt + 1;
    int*  cnt     = row_ptr + N_NODES;

    hipMemsetAsync(gcur, 0, ((size_t)NBKT * NXCD + 1) * sizeof(int), stream);

    if (use_bf16)
        k_xcast<<<(N_NODES * EMBED_DIM / 4 + 255) / 256, 256, 0, stream>>>(x, xbuf);
    k_binA<<<NTILE, 256, 0, stream>>>(rows, cols, vals, gcur, packed, ov_cnt, ov);
    k_binB<<<NBKT, 256, 0, stream>>>(gcur, packed, row_ptr, cnt);
    if (use_bf16)
        k_gather_bf16<<<(N_NODES * 64 + 255) / 256, 256, 0, stream>>>(xbuf, row_ptr, cnt, packed, out);
    else
        k_gather_f32<<<(N_NODES * 64 + 255) / 256, 256, 0, stream>>>(x, row_ptr, cnt, packed, out);
    k_overflow<<<64, 256, 0, stream>>>(x, ov_cnt, ov, out);
}